// Round 1
// baseline (1004.636 us; speedup 1.0000x reference)
//
#include <hip/hip_runtime.h>
#include <cstdint>
#include <cstddef>

typedef _Float16 half8 __attribute__((ext_vector_type(8)));
typedef _Float16 half4v __attribute__((ext_vector_type(4)));
typedef float f32x4 __attribute__((ext_vector_type(4)));

// ---------------- hf8 decode ----------------
// code: sign(1) | e(4, bias 7) | m(3). e==0 -> m * 2^-9 ; else (1+m/8)*2^(e-7).
// Branch-free-ish fp32 construction; avoids denormal arithmetic entirely.
__device__ __forceinline__ float dec_hf8(unsigned c) {
    unsigned e = (c >> 3) & 0xFu;
    unsigned m = c & 7u;
    // normal: fp32 with exponent field e+120 -> 2^(e-7), mantissa m<<20 -> (1+m/8)
    float normal = __uint_as_float(((e + 120u) << 23) | (m << 20));
    float sub = (float)m * 0x1p-9f;
    float mag = (e != 0u) ? normal : sub;
    return (c & 0x80u) ? -mag : mag;
}

// ---------------- weight pre-decode: int32 codes -> fp16 ----------------
__global__ __launch_bounds__(256) void decode_weights(const int* __restrict__ codes,
                                                      _Float16* __restrict__ out,
                                                      long long n8) {
    long long i = (long long)blockIdx.x * 256 + threadIdx.x;
    if (i >= n8) return;
    long long base = i * 8;
    int4 c0 = *(const int4*)(codes + base);
    int4 c1 = *(const int4*)(codes + base + 4);
    half8 h;
    h[0] = (_Float16)dec_hf8((unsigned)c0.x);
    h[1] = (_Float16)dec_hf8((unsigned)c0.y);
    h[2] = (_Float16)dec_hf8((unsigned)c0.z);
    h[3] = (_Float16)dec_hf8((unsigned)c0.w);
    h[4] = (_Float16)dec_hf8((unsigned)c1.x);
    h[5] = (_Float16)dec_hf8((unsigned)c1.y);
    h[6] = (_Float16)dec_hf8((unsigned)c1.z);
    h[7] = (_Float16)dec_hf8((unsigned)c1.w);
    *(half8*)(out + base) = h;
}

// ---------------- async global->LDS (16B per lane, wave-uniform LDS base) ----------------
__device__ __forceinline__ void gl_lds16(const void* g, void* l) {
    __builtin_amdgcn_global_load_lds(
        (__attribute__((address_space(1))) void*)(g),
        (__attribute__((address_space(3))) void*)(l), 16, 0, 0);
}

// ---------------- GEMM: C[M][N] = X[M][K](fp32->fp16) * W[N][K](fp16)^T + bias ----------------
// m97 structure: 128x128 tile, BK=64, 4 waves as 2x2, each wave 4x4 of 16x16x32 f16 MFMA.
__global__ __launch_bounds__(256) void hgemm_bt(const float* __restrict__ X,
                                                const _Float16* __restrict__ W,
                                                const int* __restrict__ bias_codes,
                                                float* __restrict__ C,
                                                int M, int N, int K) {
    __shared__ _Float16 As[128 * 64];
    __shared__ _Float16 Bs[128 * 64];

    const int tid  = threadIdx.x;
    const int lane = tid & 63;
    const int wid  = tid >> 6;
    const int wm   = (wid >> 1) << 6;   // wave 2x2 -> 64x64 each
    const int wn   = (wid & 1) << 6;
    const int mB   = blockIdx.y << 7;
    const int nB   = blockIdx.x << 7;

    f32x4 acc[4][4] = {};

    // A staging: 128x64 fp32 tile = 2048 chunks of 4 floats; 8 iters x 256 thr.
    // chunk = it*256+tid; row = chunk>>4 ; col4 = (chunk&15)*4  (16 threads/row -> coalesced)
    const float* aptr[8];
    int a_lds_off[8];
#pragma unroll
    for (int it = 0; it < 8; ++it) {
        int chunk = it * 256 + tid;
        int row = chunk >> 4;
        int c4 = (chunk & 15) << 2;
        aptr[it] = X + (size_t)(mB + row) * K + c4;
        a_lds_off[it] = row * 64 + c4;
    }
    // B staging: 128x64 fp16 tile = 1024 x 16B; 4 issues x 256 thr of global_load_lds.
    // chunk = is*256+tid; row = chunk>>3 ; col halfs = (chunk&7)*8
    const _Float16* bptr[4];
#pragma unroll
    for (int is = 0; is < 4; ++is) {
        int chunk = is * 256 + tid;
        int row = chunk >> 3;
        int c8 = (chunk & 7) << 3;
        bptr[is] = W + (size_t)(nB + row) * K + c8;
    }
    char* bs_base = (char*)Bs;

    const int kIters = K >> 6;
    for (int kt = 0; kt < kIters; ++kt) {
        // async B -> LDS (wave-uniform base; HW adds lane*16)
#pragma unroll
        for (int is = 0; is < 4; ++is) {
            gl_lds16(bptr[is], bs_base + ((is * 256 + (wid << 6)) << 4));
            bptr[is] += 64;
        }
        // manual A -> cvt fp16 -> LDS
#pragma unroll
        for (int it = 0; it < 8; ++it) {
            float4 v = *(const float4*)aptr[it];
            aptr[it] += 64;
            half4v h = {(_Float16)v.x, (_Float16)v.y, (_Float16)v.z, (_Float16)v.w};
            *(half4v*)(As + a_lds_off[it]) = h;
        }
        __syncthreads();  // drains vmcnt (incl. global_load_lds) + lgkm

        // MFMA: A-op row = lane&15, k = (lane>>4)*8 + j ; two 32-wide k-steps
#pragma unroll
        for (int ks = 0; ks < 2; ++ks) {
            const int kb = (ks << 5) + ((lane >> 4) << 3);
            half8 a[4], b[4];
#pragma unroll
            for (int i = 0; i < 4; ++i)
                a[i] = *(const half8*)(As + ((wm + (i << 4) + (lane & 15)) << 6) + kb);
#pragma unroll
            for (int i = 0; i < 4; ++i)
                b[i] = *(const half8*)(Bs + ((wn + (i << 4) + (lane & 15)) << 6) + kb);
#pragma unroll
            for (int mi = 0; mi < 4; ++mi)
#pragma unroll
                for (int ni = 0; ni < 4; ++ni)
                    acc[mi][ni] = __builtin_amdgcn_mfma_f32_16x16x32_f16(
                        a[mi], b[ni], acc[mi][ni], 0, 0, 0);
        }
        __syncthreads();
    }

    // Epilogue: D col = lane&15 (n), row = (lane>>4)*4 + reg (m). Bias decoded inline.
#pragma unroll
    for (int ni = 0; ni < 4; ++ni) {
        int col = nB + wn + (ni << 4) + (lane & 15);
        float bv = dec_hf8((unsigned)bias_codes[col]);
#pragma unroll
        for (int mi = 0; mi < 4; ++mi) {
            int row0 = mB + wm + (mi << 4) + ((lane >> 4) << 2);
#pragma unroll
            for (int r = 0; r < 4; ++r)
                C[(size_t)(row0 + r) * N + col] = acc[mi][ni][r] + bv;
        }
    }
}

// ---------------- correctness parachute (ws too small / odd shapes) ----------------
__global__ void naive_kernel(const float* __restrict__ X, const int* __restrict__ Wc,
                             const int* __restrict__ Bc, float* __restrict__ C,
                             int M, int N, int K) {
    long long idx = (long long)blockIdx.x * 256 + threadIdx.x;
    if (idx >= (long long)M * N) return;
    int m = (int)(idx / N);
    int n = (int)(idx % N);
    float s = dec_hf8((unsigned)Bc[n]);
    const float* x = X + (size_t)m * K;
    const int* w = Wc + (size_t)n * K;
    for (int k = 0; k < K; ++k) s += x[k] * dec_hf8((unsigned)w[k]);
    C[idx] = s;
}

extern "C" void kernel_launch(void* const* d_in, const int* in_sizes, int n_in,
                              void* d_out, int out_size, void* d_ws, size_t ws_size,
                              hipStream_t stream) {
    const float* X  = (const float*)d_in[0];   // x: fp16 promoted to fp32 by harness
    const int*   Wc = (const int*)d_in[1];     // weight codes as int32
    const int*   Bc = (const int*)d_in[2];     // bias codes as int32
    float* C = (float*)d_out;

    long long wn = (long long)in_sizes[1];     // D_OUT * D_IN
    int N = in_sizes[2];                       // D_OUT
    int K = (int)(wn / N);                     // D_IN
    int M = (int)((long long)in_sizes[0] / K); // B*S

    size_t need = (size_t)wn * sizeof(_Float16);
    bool fast = (M % 128 == 0) && (N % 128 == 0) && (K % 64 == 0) &&
                (wn % 8 == 0) && (ws_size >= need);

    if (fast) {
        _Float16* Wd = (_Float16*)d_ws;
        long long n8 = wn / 8;
        unsigned dgrid = (unsigned)((n8 + 255) / 256);
        decode_weights<<<dim3(dgrid), dim3(256), 0, stream>>>(Wc, Wd, n8);
        dim3 grid((unsigned)(N / 128), (unsigned)(M / 128));
        hgemm_bt<<<grid, dim3(256), 0, stream>>>(X, Wd, Bc, C, M, N, K);
    } else {
        long long total = (long long)M * N;
        unsigned g = (unsigned)((total + 255) / 256);
        naive_kernel<<<dim3(g), dim3(256), 0, stream>>>(X, Wc, Bc, C, M, N, K);
    }
}

// Round 2
// 814.320 us; speedup vs baseline: 1.2337x; 1.2337x over previous
//
#include <hip/hip_runtime.h>
#include <cstdint>
#include <cstddef>

typedef _Float16 half8 __attribute__((ext_vector_type(8)));
typedef _Float16 half4v __attribute__((ext_vector_type(4)));
typedef float f32x4 __attribute__((ext_vector_type(4)));

// ---------------- hf8 decode ----------------
// code: sign(1) | e(4, bias 7) | m(3). e==0 -> m * 2^-9 ; else (1+m/8)*2^(e-7).
__device__ __forceinline__ float dec_hf8(unsigned c) {
    unsigned e = (c >> 3) & 0xFu;
    unsigned m = c & 7u;
    float normal = __uint_as_float(((e + 120u) << 23) | (m << 20));
    float sub = (float)m * 0x1p-9f;
    float mag = (e != 0u) ? normal : sub;
    return (c & 0x80u) ? -mag : mag;
}

// ---------------- prep 1: weight codes (int32) -> fp16 ----------------
__global__ __launch_bounds__(256) void decode_weights(const int* __restrict__ codes,
                                                      _Float16* __restrict__ out,
                                                      long long n8) {
    long long i = (long long)blockIdx.x * 256 + threadIdx.x;
    if (i >= n8) return;
    long long base = i * 8;
    int4 c0 = *(const int4*)(codes + base);
    int4 c1 = *(const int4*)(codes + base + 4);
    half8 h;
    h[0] = (_Float16)dec_hf8((unsigned)c0.x);
    h[1] = (_Float16)dec_hf8((unsigned)c0.y);
    h[2] = (_Float16)dec_hf8((unsigned)c0.z);
    h[3] = (_Float16)dec_hf8((unsigned)c0.w);
    h[4] = (_Float16)dec_hf8((unsigned)c1.x);
    h[5] = (_Float16)dec_hf8((unsigned)c1.y);
    h[6] = (_Float16)dec_hf8((unsigned)c1.z);
    h[7] = (_Float16)dec_hf8((unsigned)c1.w);
    *(half8*)(out + base) = h;
}

// ---------------- prep 2: X fp32 -> fp16 ----------------
__global__ __launch_bounds__(256) void cvt_x(const float* __restrict__ X,
                                             _Float16* __restrict__ out,
                                             long long n8) {
    long long i = (long long)blockIdx.x * 256 + threadIdx.x;
    if (i >= n8) return;
    long long base = i * 8;
    float4 v0 = *(const float4*)(X + base);
    float4 v1 = *(const float4*)(X + base + 4);
    half8 h = {(_Float16)v0.x, (_Float16)v0.y, (_Float16)v0.z, (_Float16)v0.w,
               (_Float16)v1.x, (_Float16)v1.y, (_Float16)v1.z, (_Float16)v1.w};
    *(half8*)(out + base) = h;
}

// ---------------- async global->LDS (16B/lane, wave-uniform LDS base) ----------------
__device__ __forceinline__ void gl_lds16(const void* g, void* l) {
    __builtin_amdgcn_global_load_lds(
        (__attribute__((address_space(1))) void*)(g),
        (__attribute__((address_space(3))) void*)(l), 16, 0, 0);
}

// ---------------- GEMM: C = X16[M][K] * W16[N][K]^T + bias ----------------
// 128x128 tile, BK=64, 4 waves 2x2, each wave 4x4 of 16x16x32 f16 MFMA.
// LDS layout XOR-swizzled: row r, 16B-chunk c stored at chunk (c ^ (r&7)).
// (global_load_lds dest is wave-uniform+lane*16, so the swizzle is applied to
//  the *global source* chunk per lane; fragment reads then hit all 8 bank
//  groups across rows -> only free 2-way aliasing.)
__global__ __launch_bounds__(256) void hgemm_h16(const _Float16* __restrict__ Xh,
                                                 const _Float16* __restrict__ W,
                                                 const int* __restrict__ bias_codes,
                                                 float* __restrict__ C,
                                                 int M, int N, int K) {
    __shared__ _Float16 As[128 * 64];
    __shared__ _Float16 Bs[128 * 64];

    const int tid  = threadIdx.x;
    const int lane = tid & 63;
    const int wid  = tid >> 6;
    const int wm   = (wid >> 1) << 6;
    const int wn   = (wid & 1) << 6;

    // block swizzle: panels of 8 m-tiles per n-tile for W-panel L2 reuse
    const int nTiles = gridDim.x, mTiles = gridDim.y;
    int bid = blockIdx.y * nTiles + blockIdx.x;
    const int GM = 8;
    int group = bid / (GM * nTiles);
    int inGrp = bid % (GM * nTiles);
    int mStart = group * GM;
    int gm = (mTiles - mStart < GM) ? (mTiles - mStart) : GM;
    const int mB = (mStart + inGrp % gm) << 7;
    const int nB = (inGrp / gm) << 7;

    f32x4 acc[4][4] = {};

    // staging: 1024 chunks of 16B per tile; 4 issues x 256 threads.
    // linear chunk p = is*256 + tid ; row = p>>3 ; global chunk = (p&7) ^ (row&7)
    const _Float16* aptr[4];
    const _Float16* bptr[4];
#pragma unroll
    for (int is = 0; is < 4; ++is) {
        int p = is * 256 + tid;
        int row = p >> 3;
        int g = (p & 7) ^ (row & 7);
        aptr[is] = Xh + (size_t)(mB + row) * K + (g << 3);
        bptr[is] = W + (size_t)(nB + row) * K + (g << 3);
    }
    char* as_base = (char*)As;
    char* bs_base = (char*)Bs;
    const int ldsWave = wid << 6;  // wave-uniform chunk base within an issue

    const int rsw = lane & 7;   // fragment-row swizzle key (row&7 == lane&7)
    const int qk  = lane >> 4;  // k-chunk within a 32-wide step
    const int fr  = lane & 15;  // fragment row

    const int kIters = K >> 6;
    for (int kt = 0; kt < kIters; ++kt) {
#pragma unroll
        for (int is = 0; is < 4; ++is) {
            gl_lds16(aptr[is], as_base + ((is * 256 + ldsWave) << 4));
            aptr[is] += 64;
        }
#pragma unroll
        for (int is = 0; is < 4; ++is) {
            gl_lds16(bptr[is], bs_base + ((is * 256 + ldsWave) << 4));
            bptr[is] += 64;
        }
        __syncthreads();  // drains vmcnt (global_load_lds) for all waves

#pragma unroll
        for (int ks = 0; ks < 2; ++ks) {
            const int coff = (((ks << 2) + qk) ^ rsw) << 3;  // swizzled half-offset in row
            half8 a[4], b[4];
#pragma unroll
            for (int i = 0; i < 4; ++i)
                a[i] = *(const half8*)(As + ((wm + (i << 4) + fr) << 6) + coff);
#pragma unroll
            for (int i = 0; i < 4; ++i)
                b[i] = *(const half8*)(Bs + ((wn + (i << 4) + fr) << 6) + coff);
#pragma unroll
            for (int mi = 0; mi < 4; ++mi)
#pragma unroll
                for (int ni = 0; ni < 4; ++ni)
                    acc[mi][ni] = __builtin_amdgcn_mfma_f32_16x16x32_f16(
                        a[mi], b[ni], acc[mi][ni], 0, 0, 0);
        }
        __syncthreads();
    }

    // Epilogue: D col = lane&15 (n), row = (lane>>4)*4 + reg (m).
#pragma unroll
    for (int ni = 0; ni < 4; ++ni) {
        int col = nB + wn + (ni << 4) + fr;
        float bv = dec_hf8((unsigned)bias_codes[col]);
#pragma unroll
        for (int mi = 0; mi < 4; ++mi) {
            int row0 = mB + wm + (mi << 4) + ((lane >> 4) << 2);
#pragma unroll
            for (int r = 0; r < 4; ++r)
                C[(size_t)(row0 + r) * N + col] = acc[mi][ni][r] + bv;
        }
    }
}

// ---------------- fallback: fp32-A staging GEMM (round-1, known correct) ----------------
__global__ __launch_bounds__(256) void hgemm_bt(const float* __restrict__ X,
                                                const _Float16* __restrict__ W,
                                                const int* __restrict__ bias_codes,
                                                float* __restrict__ C,
                                                int M, int N, int K) {
    __shared__ _Float16 As[128 * 64];
    __shared__ _Float16 Bs[128 * 64];
    const int tid  = threadIdx.x;
    const int lane = tid & 63;
    const int wid  = tid >> 6;
    const int wm   = (wid >> 1) << 6;
    const int wn   = (wid & 1) << 6;
    const int mB   = blockIdx.y << 7;
    const int nB   = blockIdx.x << 7;
    f32x4 acc[4][4] = {};
    const float* aptr[8];
    int a_lds_off[8];
#pragma unroll
    for (int it = 0; it < 8; ++it) {
        int chunk = it * 256 + tid;
        int row = chunk >> 4;
        int c4 = (chunk & 15) << 2;
        aptr[it] = X + (size_t)(mB + row) * K + c4;
        a_lds_off[it] = row * 64 + c4;
    }
    const _Float16* bptr[4];
#pragma unroll
    for (int is = 0; is < 4; ++is) {
        int chunk = is * 256 + tid;
        int row = chunk >> 3;
        int c8 = (chunk & 7) << 3;
        bptr[is] = W + (size_t)(nB + row) * K + c8;
    }
    char* bs_base = (char*)Bs;
    const int kIters = K >> 6;
    for (int kt = 0; kt < kIters; ++kt) {
#pragma unroll
        for (int is = 0; is < 4; ++is) {
            gl_lds16(bptr[is], bs_base + ((is * 256 + (wid << 6)) << 4));
            bptr[is] += 64;
        }
#pragma unroll
        for (int it = 0; it < 8; ++it) {
            float4 v = *(const float4*)aptr[it];
            aptr[it] += 64;
            half4v h = {(_Float16)v.x, (_Float16)v.y, (_Float16)v.z, (_Float16)v.w};
            *(half4v*)(As + a_lds_off[it]) = h;
        }
        __syncthreads();
#pragma unroll
        for (int ks = 0; ks < 2; ++ks) {
            const int kb = (ks << 5) + ((lane >> 4) << 3);
            half8 a[4], b[4];
#pragma unroll
            for (int i = 0; i < 4; ++i)
                a[i] = *(const half8*)(As + ((wm + (i << 4) + (lane & 15)) << 6) + kb);
#pragma unroll
            for (int i = 0; i < 4; ++i)
                b[i] = *(const half8*)(Bs + ((wn + (i << 4) + (lane & 15)) << 6) + kb);
#pragma unroll
            for (int mi = 0; mi < 4; ++mi)
#pragma unroll
                for (int ni = 0; ni < 4; ++ni)
                    acc[mi][ni] = __builtin_amdgcn_mfma_f32_16x16x32_f16(
                        a[mi], b[ni], acc[mi][ni], 0, 0, 0);
        }
        __syncthreads();
    }
#pragma unroll
    for (int ni = 0; ni < 4; ++ni) {
        int col = nB + wn + (ni << 4) + (lane & 15);
        float bv = dec_hf8((unsigned)bias_codes[col]);
#pragma unroll
        for (int mi = 0; mi < 4; ++mi) {
            int row0 = mB + wm + (mi << 4) + ((lane >> 4) << 2);
#pragma unroll
            for (int r = 0; r < 4; ++r)
                C[(size_t)(row0 + r) * N + col] = acc[mi][ni][r] + bv;
        }
    }
}

// ---------------- correctness parachute ----------------
__global__ void naive_kernel(const float* __restrict__ X, const int* __restrict__ Wc,
                             const int* __restrict__ Bc, float* __restrict__ C,
                             int M, int N, int K) {
    long long idx = (long long)blockIdx.x * 256 + threadIdx.x;
    if (idx >= (long long)M * N) return;
    int m = (int)(idx / N);
    int n = (int)(idx % N);
    float s = dec_hf8((unsigned)Bc[n]);
    const float* x = X + (size_t)m * K;
    const int* w = Wc + (size_t)n * K;
    for (int k = 0; k < K; ++k) s += x[k] * dec_hf8((unsigned)w[k]);
    C[idx] = s;
}

extern "C" void kernel_launch(void* const* d_in, const int* in_sizes, int n_in,
                              void* d_out, int out_size, void* d_ws, size_t ws_size,
                              hipStream_t stream) {
    const float* X  = (const float*)d_in[0];   // x: fp16 promoted to fp32 by harness
    const int*   Wc = (const int*)d_in[1];     // weight codes as int32
    const int*   Bc = (const int*)d_in[2];     // bias codes as int32
    float* C = (float*)d_out;

    long long wn = (long long)in_sizes[1];     // D_OUT * D_IN
    int N = in_sizes[2];                       // D_OUT
    int K = (int)(wn / N);                     // D_IN
    long long xn = (long long)in_sizes[0];
    int M = (int)(xn / K);                     // B*S

    size_t needW = (size_t)wn * sizeof(_Float16);
    size_t needX = (size_t)xn * sizeof(_Float16);
    bool shapes_ok = (M % 128 == 0) && (N % 128 == 0) && (K % 64 == 0) &&
                     (wn % 8 == 0) && (xn % 8 == 0);

    if (shapes_ok && ws_size >= needW + needX) {
        _Float16* Wd = (_Float16*)d_ws;
        _Float16* Xh = (_Float16*)((char*)d_ws + needW);
        decode_weights<<<dim3((unsigned)((wn / 8 + 255) / 256)), dim3(256), 0, stream>>>(Wc, Wd, wn / 8);
        cvt_x<<<dim3((unsigned)((xn / 8 + 255) / 256)), dim3(256), 0, stream>>>(X, Xh, xn / 8);
        dim3 grid((unsigned)(N / 128), (unsigned)(M / 128));
        hgemm_h16<<<grid, dim3(256), 0, stream>>>(Xh, Wd, Bc, C, M, N, K);
    } else if (shapes_ok && ws_size >= needW) {
        _Float16* Wd = (_Float16*)d_ws;
        decode_weights<<<dim3((unsigned)((wn / 8 + 255) / 256)), dim3(256), 0, stream>>>(Wc, Wd, wn / 8);
        dim3 grid((unsigned)(N / 128), (unsigned)(M / 128));
        hgemm_bt<<<grid, dim3(256), 0, stream>>>(X, Wd, Bc, C, M, N, K);
    } else {
        long long total = (long long)M * N;
        naive_kernel<<<dim3((unsigned)((total + 255) / 256)), dim3(256), 0, stream>>>(X, Wc, Bc, C, M, N, K);
    }
}

// Round 3
// 795.600 us; speedup vs baseline: 1.2627x; 1.0235x over previous
//
#include <hip/hip_runtime.h>
#include <cstdint>
#include <cstddef>

typedef _Float16 half8 __attribute__((ext_vector_type(8)));
typedef _Float16 half4v __attribute__((ext_vector_type(4)));
typedef float f32x4 __attribute__((ext_vector_type(4)));
typedef float f32x16 __attribute__((ext_vector_type(16)));

// ---------------- hf8 decode ----------------
// code: sign(1) | e(4, bias 7) | m(3). e==0 -> m * 2^-9 ; else (1+m/8)*2^(e-7).
__device__ __forceinline__ float dec_hf8(unsigned c) {
    unsigned e = (c >> 3) & 0xFu;
    unsigned m = c & 7u;
    float normal = __uint_as_float(((e + 120u) << 23) | (m << 20));
    float sub = (float)m * 0x1p-9f;
    float mag = (e != 0u) ? normal : sub;
    return (c & 0x80u) ? -mag : mag;
}

// ---------------- prep 1: weight codes (int32) -> fp16 ----------------
__global__ __launch_bounds__(256) void decode_weights(const int* __restrict__ codes,
                                                      _Float16* __restrict__ out,
                                                      long long n8) {
    long long i = (long long)blockIdx.x * 256 + threadIdx.x;
    if (i >= n8) return;
    long long base = i * 8;
    int4 c0 = *(const int4*)(codes + base);
    int4 c1 = *(const int4*)(codes + base + 4);
    half8 h;
    h[0] = (_Float16)dec_hf8((unsigned)c0.x);
    h[1] = (_Float16)dec_hf8((unsigned)c0.y);
    h[2] = (_Float16)dec_hf8((unsigned)c0.z);
    h[3] = (_Float16)dec_hf8((unsigned)c0.w);
    h[4] = (_Float16)dec_hf8((unsigned)c1.x);
    h[5] = (_Float16)dec_hf8((unsigned)c1.y);
    h[6] = (_Float16)dec_hf8((unsigned)c1.z);
    h[7] = (_Float16)dec_hf8((unsigned)c1.w);
    *(half8*)(out + base) = h;
}

// ---------------- prep 2: X fp32 -> fp16 ----------------
__global__ __launch_bounds__(256) void cvt_x(const float* __restrict__ X,
                                             _Float16* __restrict__ out,
                                             long long n8) {
    long long i = (long long)blockIdx.x * 256 + threadIdx.x;
    if (i >= n8) return;
    long long base = i * 8;
    float4 v0 = *(const float4*)(X + base);
    float4 v1 = *(const float4*)(X + base + 4);
    half8 h = {(_Float16)v0.x, (_Float16)v0.y, (_Float16)v0.z, (_Float16)v0.w,
               (_Float16)v1.x, (_Float16)v1.y, (_Float16)v1.z, (_Float16)v1.w};
    *(half8*)(out + base) = h;
}

// ---------------- async global->LDS (16B/lane, wave-uniform LDS base) ----------------
__device__ __forceinline__ void gl_lds16(const void* g, void* l) {
    __builtin_amdgcn_global_load_lds(
        (__attribute__((address_space(1))) void*)(g),
        (__attribute__((address_space(3))) void*)(l), 16, 0, 0);
}

// ---------------- GEMM: C = X16[M][K] * W16[N][K]^T + bias ----------------
// 128x128 tile, BK=64, 4 waves 2x2; each wave = 2x2 of 32x32x16 f16 MFMA.
// LDS XOR-swizzled: row r, 16B-chunk c stored at chunk (c ^ (r&7)).
// 32x32x16 A/B frag: row/col = lane&31, k = (lane>>5)*8 + j.
// 32x32 C/D: col = lane&31, row = (reg&3) + 8*(reg>>2) + 4*(lane>>5)  [m74/m101].
__global__ __launch_bounds__(256) void hgemm_h32(const _Float16* __restrict__ Xh,
                                                 const _Float16* __restrict__ W,
                                                 const int* __restrict__ bias_codes,
                                                 float* __restrict__ C,
                                                 int M, int N, int K) {
    __shared__ _Float16 As[128 * 64];
    __shared__ _Float16 Bs[128 * 64];

    const int tid  = threadIdx.x;
    const int lane = tid & 63;
    const int wid  = tid >> 6;
    const int wm   = (wid >> 1) << 6;
    const int wn   = (wid & 1) << 6;

    // block swizzle: panels of 8 m-tiles per n-tile for W-panel L2 reuse
    const int nTiles = gridDim.x, mTiles = gridDim.y;
    int bid = blockIdx.y * nTiles + blockIdx.x;
    const int GM = 8;
    int group = bid / (GM * nTiles);
    int inGrp = bid % (GM * nTiles);
    int mStart = group * GM;
    int gm = (mTiles - mStart < GM) ? (mTiles - mStart) : GM;
    const int mB = (mStart + inGrp % gm) << 7;
    const int nB = (inGrp / gm) << 7;

    f32x16 acc[2][2] = {};

    // staging: 1024 chunks of 16B per tile; 4 issues x 256 threads.
    // p = is*256 + tid ; row = p>>3 ; global chunk = (p&7) ^ (row&7)
    const _Float16* aptr[4];
    const _Float16* bptr[4];
#pragma unroll
    for (int is = 0; is < 4; ++is) {
        int p = is * 256 + tid;
        int row = p >> 3;
        int g = (p & 7) ^ (row & 7);
        aptr[is] = Xh + (size_t)(mB + row) * K + (g << 3);
        bptr[is] = W + (size_t)(nB + row) * K + (g << 3);
    }
    char* as_base = (char*)As;
    char* bs_base = (char*)Bs;
    const int ldsWave = wid << 6;

    const int fr  = lane & 31;   // fragment row/col
    const int kh  = lane >> 5;   // k-half selector (8 halfs each)
    const int rsw = fr & 7;      // row swizzle key

    const int kIters = K >> 6;
    for (int kt = 0; kt < kIters; ++kt) {
#pragma unroll
        for (int is = 0; is < 4; ++is) {
            gl_lds16(aptr[is], as_base + ((is * 256 + ldsWave) << 4));
            aptr[is] += 64;
        }
#pragma unroll
        for (int is = 0; is < 4; ++is) {
            gl_lds16(bptr[is], bs_base + ((is * 256 + ldsWave) << 4));
            bptr[is] += 64;
        }
        __syncthreads();  // drains vmcnt (global_load_lds) for all waves

        // 4 k-steps of 16; lane reads chunk (2*ks + kh) ^ (row&7) of its row
#pragma unroll
        for (int ks = 0; ks < 4; ++ks) {
            const int coff = (((ks << 1) + kh) ^ rsw) << 3;  // half-offset in row
            half8 a[2], b[2];
#pragma unroll
            for (int i = 0; i < 2; ++i)
                a[i] = *(const half8*)(As + ((wm + (i << 5) + fr) << 6) + coff);
#pragma unroll
            for (int i = 0; i < 2; ++i)
                b[i] = *(const half8*)(Bs + ((wn + (i << 5) + fr) << 6) + coff);
#pragma unroll
            for (int mi = 0; mi < 2; ++mi)
#pragma unroll
                for (int ni = 0; ni < 2; ++ni)
                    acc[mi][ni] = __builtin_amdgcn_mfma_f32_32x32x16_f16(
                        a[mi], b[ni], acc[mi][ni], 0, 0, 0);
        }
        __syncthreads();
    }

    // Epilogue: col = lane&31, row = (reg&3) + 8*(reg>>2) + 4*(lane>>5)
#pragma unroll
    for (int ni = 0; ni < 2; ++ni) {
        int col = nB + wn + (ni << 5) + fr;
        float bv = dec_hf8((unsigned)bias_codes[col]);
#pragma unroll
        for (int mi = 0; mi < 2; ++mi) {
            int rbase = mB + wm + (mi << 5) + (kh << 2);
#pragma unroll
            for (int r = 0; r < 16; ++r) {
                int row = rbase + (r & 3) + ((r >> 2) << 3);
                C[(size_t)row * N + col] = acc[mi][ni][r] + bv;
            }
        }
    }
}

// ---------------- fallback: fp32-A staging GEMM (round-1, known correct) ----------------
__global__ __launch_bounds__(256) void hgemm_bt(const float* __restrict__ X,
                                                const _Float16* __restrict__ W,
                                                const int* __restrict__ bias_codes,
                                                float* __restrict__ C,
                                                int M, int N, int K) {
    __shared__ _Float16 As[128 * 64];
    __shared__ _Float16 Bs[128 * 64];
    const int tid  = threadIdx.x;
    const int lane = tid & 63;
    const int wid  = tid >> 6;
    const int wm   = (wid >> 1) << 6;
    const int wn   = (wid & 1) << 6;
    const int mB   = blockIdx.y << 7;
    const int nB   = blockIdx.x << 7;
    f32x4 acc[4][4] = {};
    const float* aptr[8];
    int a_lds_off[8];
#pragma unroll
    for (int it = 0; it < 8; ++it) {
        int chunk = it * 256 + tid;
        int row = chunk >> 4;
        int c4 = (chunk & 15) << 2;
        aptr[it] = X + (size_t)(mB + row) * K + c4;
        a_lds_off[it] = row * 64 + c4;
    }
    const _Float16* bptr[4];
#pragma unroll
    for (int is = 0; is < 4; ++is) {
        int chunk = is * 256 + tid;
        int row = chunk >> 3;
        int c8 = (chunk & 7) << 3;
        bptr[is] = W + (size_t)(nB + row) * K + c8;
    }
    char* bs_base = (char*)Bs;
    const int kIters = K >> 6;
    for (int kt = 0; kt < kIters; ++kt) {
#pragma unroll
        for (int is = 0; is < 4; ++is) {
            gl_lds16(bptr[is], bs_base + ((is * 256 + (wid << 6)) << 4));
            bptr[is] += 64;
        }
#pragma unroll
        for (int it = 0; it < 8; ++it) {
            float4 v = *(const float4*)aptr[it];
            aptr[it] += 64;
            half4v h = {(_Float16)v.x, (_Float16)v.y, (_Float16)v.z, (_Float16)v.w};
            *(half4v*)(As + a_lds_off[it]) = h;
        }
        __syncthreads();
#pragma unroll
        for (int ks = 0; ks < 2; ++ks) {
            const int kb = (ks << 5) + ((lane >> 4) << 3);
            half8 a[4], b[4];
#pragma unroll
            for (int i = 0; i < 4; ++i)
                a[i] = *(const half8*)(As + ((wm + (i << 4) + (lane & 15)) << 6) + kb);
#pragma unroll
            for (int i = 0; i < 4; ++i)
                b[i] = *(const half8*)(Bs + ((wn + (i << 4) + (lane & 15)) << 6) + kb);
#pragma unroll
            for (int mi = 0; mi < 4; ++mi)
#pragma unroll
                for (int ni = 0; ni < 4; ++ni)
                    acc[mi][ni] = __builtin_amdgcn_mfma_f32_16x16x32_f16(
                        a[mi], b[ni], acc[mi][ni], 0, 0, 0);
        }
        __syncthreads();
    }
#pragma unroll
    for (int ni = 0; ni < 4; ++ni) {
        int col = nB + wn + (ni << 4) + (lane & 15);
        float bv = dec_hf8((unsigned)bias_codes[col]);
#pragma unroll
        for (int mi = 0; mi < 4; ++mi) {
            int row0 = mB + wm + (mi << 4) + ((lane >> 4) << 2);
#pragma unroll
            for (int r = 0; r < 4; ++r)
                C[(size_t)(row0 + r) * N + col] = acc[mi][ni][r] + bv;
        }
    }
}

// ---------------- correctness parachute ----------------
__global__ void naive_kernel(const float* __restrict__ X, const int* __restrict__ Wc,
                             const int* __restrict__ Bc, float* __restrict__ C,
                             int M, int N, int K) {
    long long idx = (long long)blockIdx.x * 256 + threadIdx.x;
    if (idx >= (long long)M * N) return;
    int m = (int)(idx / N);
    int n = (int)(idx % N);
    float s = dec_hf8((unsigned)Bc[n]);
    const float* x = X + (size_t)m * K;
    const int* w = Wc + (size_t)n * K;
    for (int k = 0; k < K; ++k) s += x[k] * dec_hf8((unsigned)w[k]);
    C[idx] = s;
}

extern "C" void kernel_launch(void* const* d_in, const int* in_sizes, int n_in,
                              void* d_out, int out_size, void* d_ws, size_t ws_size,
                              hipStream_t stream) {
    const float* X  = (const float*)d_in[0];   // x: fp16 promoted to fp32 by harness
    const int*   Wc = (const int*)d_in[1];     // weight codes as int32
    const int*   Bc = (const int*)d_in[2];     // bias codes as int32
    float* C = (float*)d_out;

    long long wn = (long long)in_sizes[1];     // D_OUT * D_IN
    int N = in_sizes[2];                       // D_OUT
    int K = (int)(wn / N);                     // D_IN
    long long xn = (long long)in_sizes[0];
    int M = (int)(xn / K);                     // B*S

    size_t needW = (size_t)wn * sizeof(_Float16);
    size_t needX = (size_t)xn * sizeof(_Float16);
    bool shapes_ok = (M % 128 == 0) && (N % 128 == 0) && (K % 64 == 0) &&
                     (wn % 8 == 0) && (xn % 8 == 0);

    if (shapes_ok && ws_size >= needW + needX) {
        _Float16* Wd = (_Float16*)d_ws;
        _Float16* Xh = (_Float16*)((char*)d_ws + needW);
        decode_weights<<<dim3((unsigned)((wn / 8 + 255) / 256)), dim3(256), 0, stream>>>(Wc, Wd, wn / 8);
        cvt_x<<<dim3((unsigned)((xn / 8 + 255) / 256)), dim3(256), 0, stream>>>(X, Xh, xn / 8);
        dim3 grid((unsigned)(N / 128), (unsigned)(M / 128));
        hgemm_h32<<<grid, dim3(256), 0, stream>>>(Xh, Wd, Bc, C, M, N, K);
    } else if (shapes_ok && ws_size >= needW) {
        _Float16* Wd = (_Float16*)d_ws;
        decode_weights<<<dim3((unsigned)((wn / 8 + 255) / 256)), dim3(256), 0, stream>>>(Wc, Wd, wn / 8);
        dim3 grid((unsigned)(N / 128), (unsigned)(M / 128));
        hgemm_bt<<<grid, dim3(256), 0, stream>>>(X, Wd, Bc, C, M, N, K);
    } else {
        long long total = (long long)M * N;
        naive_kernel<<<dim3((unsigned)((total + 255) / 256)), dim3(256), 0, stream>>>(X, Wc, Bc, C, M, N, K);
    }
}